// Round 17
// baseline (215.349 us; speedup 1.0000x reference)
//
#include <hip/hip_runtime.h>
#include <math.h>

// ---------------------------------------------------------------------------
// 2-layer GCN:  out = gcn(relu(gcn(x, W1, b1)), W2, b2)
// gcn(x,W,b)[c] = dinv[c] * ( dinv[c]*xw[c] + sum_{edges r->c} dinv[r]*xw[r] ) + b
//   where xw = x @ W (UNSCALED in y buffers), dinv = rsqrt(1 + indeg)
// Slot-CSR (CAP=32) via two-pass rank build. GEMM1 = 128x256 wide tile.
// zero+Wprep -> count(2048, pure) -> GEMM1||dinv||fill -> agg1 2x128 ->
// GEMM2 -> agg2 2x64 (all agg passes sequential: L2 working-set split).
// ---------------------------------------------------------------------------

typedef _Float16 h8 __attribute__((ext_vector_type(8)));
typedef float    f32x4 __attribute__((ext_vector_type(4)));

#define CAP 32   // slots per node; overflow list handles adversarial degrees

// zero deg/govf (blocks [0,zb)) + both weight transposes (rest)
__global__ void k_zero_prep(int* __restrict__ deg, int* __restrict__ govf, int N,
                            const float* __restrict__ W1, const float* __restrict__ W2,
                            _Float16* __restrict__ wt1, _Float16* __restrict__ wt2,
                            int K, int n1, int n2, int zb)
{
    if ((int)blockIdx.x < zb) {
        int i = blockIdx.x * blockDim.x + threadIdx.x;
        if (i < N) deg[i] = 0;
        if (i == 0) *govf = 0;
    } else {
        int i = (blockIdx.x - zb) * blockDim.x + threadIdx.x;
        int c1 = K * n1;
        if (i < c1) {
            int k = i / n1, n = i % n1;
            wt1[(long)n * K + k] = (_Float16)W1[i];
        } else if (i < c1 + K * n2) {
            int j = i - c1;
            int k = j / n2, n = j % n2;
            wt2[(long)n * K + k] = (_Float16)W2[j];
        }
    }
}

// pure degree count; atomicAdd return = edge's rank within its node
__global__ __launch_bounds__(256) void k_count(
    const int* __restrict__ col, int E, int* __restrict__ deg, int* __restrict__ rank)
{
    int i = blockIdx.x * blockDim.x + threadIdx.x;
    int s = gridDim.x * blockDim.x;
    for (int e = i; e < E; e += s) rank[e] = atomicAdd(&deg[col[e]], 1);
}

// ---- GEMM1 body: 128x256 tile (full NC), 512 threads = 8 waves (2x4),
// each wave 64x64 via 4x4 mfma_f32_16x16x32_f16. Reads fp32 X once. ----
__device__ __forceinline__ void gemm1_body(
    const float* __restrict__ X32, const _Float16* __restrict__ Wt,
    _Float16* __restrict__ Y, int M, int K, int by)
{
    __shared__ _Float16 As[128][40];
    __shared__ _Float16 Bs[256][40];

    const int bm = by * 128;
    const int tid = threadIdx.x;
    const int w = tid >> 6, l = tid & 63;
    const int wm = (w >> 2) * 64, wn = (w & 3) * 64;
    const int lr = l & 15, lg = l >> 4;

    const int arow = tid >> 2, acol = (tid & 3) * 8;
    const int brow = tid >> 1, bcol = (tid & 1) * 16;

    f32x4 acc[4][4];
    #pragma unroll
    for (int i = 0; i < 4; i++)
        #pragma unroll
        for (int j = 0; j < 4; j++)
            acc[i][j] = (f32x4){0.f, 0.f, 0.f, 0.f};

    float4 pf0, pf1;
    h8 pb0, pb1;

    auto loadA = [&](int k0) {
        int gm = bm + arow; if (gm >= M) gm = M - 1;
        pf0 = *reinterpret_cast<const float4*>(&X32[(long)gm * K + k0 + acol]);
        pf1 = *reinterpret_cast<const float4*>(&X32[(long)gm * K + k0 + acol + 4]);
    };
    auto loadB = [&](int k0) {
        pb0 = *reinterpret_cast<const h8*>(&Wt[(long)brow * K + k0 + bcol]);
        pb1 = *reinterpret_cast<const h8*>(&Wt[(long)brow * K + k0 + bcol + 8]);
    };

    loadA(0); loadB(0);
    for (int k0 = 0; k0 < K; k0 += 32) {
        h8 hv;
        hv[0] = (_Float16)pf0.x; hv[1] = (_Float16)pf0.y;
        hv[2] = (_Float16)pf0.z; hv[3] = (_Float16)pf0.w;
        hv[4] = (_Float16)pf1.x; hv[5] = (_Float16)pf1.y;
        hv[6] = (_Float16)pf1.z; hv[7] = (_Float16)pf1.w;
        *reinterpret_cast<h8*>(&As[arow][acol]) = hv;
        *reinterpret_cast<h8*>(&Bs[brow][bcol]) = pb0;
        *reinterpret_cast<h8*>(&Bs[brow][bcol + 8]) = pb1;
        __syncthreads();

        if (k0 + 32 < K) { loadA(k0 + 32); loadB(k0 + 32); }

        h8 a[4], b[4];
        #pragma unroll
        for (int i = 0; i < 4; i++)
            a[i] = *reinterpret_cast<const h8*>(&As[wm + i * 16 + lr][lg * 8]);
        #pragma unroll
        for (int j = 0; j < 4; j++)
            b[j] = *reinterpret_cast<const h8*>(&Bs[wn + j * 16 + lr][lg * 8]);
        #pragma unroll
        for (int i = 0; i < 4; i++)
            #pragma unroll
            for (int j = 0; j < 4; j++)
                acc[i][j] = __builtin_amdgcn_mfma_f32_16x16x32_f16(
                    a[i], b[j], acc[i][j], 0, 0, 0);
        __syncthreads();
    }

    #pragma unroll
    for (int i = 0; i < 4; i++) {
        #pragma unroll
        for (int r = 0; r < 4; r++) {
            int gm = bm + wm + i * 16 + lg * 4 + r;
            if (gm < M) {
                #pragma unroll
                for (int j = 0; j < 4; j++)
                    Y[(long)gm * 256 + wn + j * 16 + lr] =
                        (_Float16)acc[i][j][r];
            }
        }
    }
}

// Fused (512 threads): blocks [0,ngb) = GEMM1 wide tiles; [ngb,ngb+zb5) =
// dinv; rest = atomic-free slot fill via rank.
__global__ __launch_bounds__(512) void k_gemm_fill(
    const float* __restrict__ X32, const _Float16* __restrict__ Wt,
    _Float16* __restrict__ Y, int M, int K, int ngb,
    const int* __restrict__ row, const int* __restrict__ col,
    const int* __restrict__ rank, int E,
    const int* __restrict__ deg, float* __restrict__ dinv, int N,
    int* __restrict__ srcidx, int2* __restrict__ ovf, int* __restrict__ govf,
    int zb5)
{
    if ((int)blockIdx.x < ngb) {
        gemm1_body(X32, Wt, Y, M, K, blockIdx.x);
        return;
    }
    if ((int)blockIdx.x < ngb + zb5) {
        int i = (blockIdx.x - ngb) * blockDim.x + threadIdx.x;
        if (i < N) dinv[i] = rsqrtf(1.f + (float)deg[i]);
        return;
    }
    int g = (blockIdx.x - ngb - zb5) * blockDim.x + threadIdx.x;
    int nthreads = (gridDim.x - ngb - zb5) * blockDim.x;
    if ((E & 3) == 0) {
        int G4 = E >> 2;
        for (int q = g; q < G4; q += nthreads) {
            int e = q << 2;
            int4 c4 = *reinterpret_cast<const int4*>(&col[e]);
            int4 r4 = *reinterpret_cast<const int4*>(&row[e]);
            int4 k4 = *reinterpret_cast<const int4*>(&rank[e]);
            if (k4.x < CAP) srcidx[c4.x * CAP + k4.x] = r4.x;
            else { int o = atomicAdd(govf, 1); ovf[o] = make_int2(r4.x, c4.x); }
            if (k4.y < CAP) srcidx[c4.y * CAP + k4.y] = r4.y;
            else { int o = atomicAdd(govf, 1); ovf[o] = make_int2(r4.y, c4.y); }
            if (k4.z < CAP) srcidx[c4.z * CAP + k4.z] = r4.z;
            else { int o = atomicAdd(govf, 1); ovf[o] = make_int2(r4.z, c4.z); }
            if (k4.w < CAP) srcidx[c4.w * CAP + k4.w] = r4.w;
            else { int o = atomicAdd(govf, 1); ovf[o] = make_int2(r4.w, c4.w); }
        }
    } else {
        for (int e = g; e < E; e += nthreads) {
            int c = col[e], r = row[e], k = rank[e];
            if (k < CAP) srcidx[c * CAP + k] = r;
            else { int o = atomicAdd(govf, 1); ovf[o] = make_int2(r, c); }
        }
    }
}

// ---- GEMM2: 128x128 tile, 256 threads, fp16 input ----
__global__ __launch_bounds__(256) void k_gemm16(
    const _Float16* __restrict__ X16, const _Float16* __restrict__ Wt,
    _Float16* __restrict__ Y, int M, int K, int NC)
{
    __shared__ _Float16 As[128][40];
    __shared__ _Float16 Bs[128][40];

    const int bn = blockIdx.x * 128;
    const int bm = blockIdx.y * 128;
    const int tid = threadIdx.x;
    const int w = tid >> 6, l = tid & 63;
    const int wm = (w >> 1) * 64, wn = (w & 1) * 64;
    const int lr = l & 15, lg = l >> 4;
    const int xrow = tid >> 1, xcol = (tid & 1) * 16;

    f32x4 acc[4][4];
    #pragma unroll
    for (int i = 0; i < 4; i++)
        #pragma unroll
        for (int j = 0; j < 4; j++)
            acc[i][j] = (f32x4){0.f, 0.f, 0.f, 0.f};

    h8 pa0, pa1, pb0, pb1;
    auto loadA = [&](int k0) {
        int gm = bm + xrow; if (gm >= M) gm = M - 1;
        pa0 = *reinterpret_cast<const h8*>(&X16[(long)gm * K + k0 + xcol]);
        pa1 = *reinterpret_cast<const h8*>(&X16[(long)gm * K + k0 + xcol + 8]);
    };
    auto loadB = [&](int k0) {
        pb0 = *reinterpret_cast<const h8*>(&Wt[(long)(bn + xrow) * K + k0 + xcol]);
        pb1 = *reinterpret_cast<const h8*>(&Wt[(long)(bn + xrow) * K + k0 + xcol + 8]);
    };

    loadA(0); loadB(0);
    for (int k0 = 0; k0 < K; k0 += 32) {
        *reinterpret_cast<h8*>(&As[xrow][xcol]) = pa0;
        *reinterpret_cast<h8*>(&As[xrow][xcol + 8]) = pa1;
        *reinterpret_cast<h8*>(&Bs[xrow][xcol]) = pb0;
        *reinterpret_cast<h8*>(&Bs[xrow][xcol + 8]) = pb1;
        __syncthreads();

        if (k0 + 32 < K) { loadA(k0 + 32); loadB(k0 + 32); }

        h8 a[4], b[4];
        #pragma unroll
        for (int i = 0; i < 4; i++)
            a[i] = *reinterpret_cast<const h8*>(&As[wm + i * 16 + lr][lg * 8]);
        #pragma unroll
        for (int j = 0; j < 4; j++)
            b[j] = *reinterpret_cast<const h8*>(&Bs[wn + j * 16 + lr][lg * 8]);
        #pragma unroll
        for (int i = 0; i < 4; i++)
            #pragma unroll
            for (int j = 0; j < 4; j++)
                acc[i][j] = __builtin_amdgcn_mfma_f32_16x16x32_f16(
                    a[i], b[j], acc[i][j], 0, 0, 0);
        __syncthreads();
    }

    #pragma unroll
    for (int i = 0; i < 4; i++) {
        #pragma unroll
        for (int r = 0; r < 4; r++) {
            int gm = bm + wm + i * 16 + lg * 4 + r;
            if (gm < M) {
                #pragma unroll
                for (int j = 0; j < 4; j++)
                    Y[(long)gm * NC + bn + wn + j * 16 + lr] =
                        (_Float16)acc[i][j][r];
            }
        }
    }
}

// out[node][fo:fo+LPR*8] = act( dc*( dc*Y[node] + sum_e dinv[r]*Y[r] ) + bias )
// One wave per node, slot-CSR; LPR lanes per row slice (16B/lane),
// G = 64/LPR sub-groups; each sub-group loads 4 contiguous slots as int4
// -> 4G edges in flight; fp16-source fma (v_fma_mix).
template<int LPR, bool F16OUT, bool RELU>
__global__ __launch_bounds__(256) void k_agg(
    const int* __restrict__ deg, const float* __restrict__ dinv,
    const int* __restrict__ srcidx,
    const int2* __restrict__ ovf, const int* __restrict__ govf,
    const _Float16* __restrict__ Y, const float* __restrict__ bias,
    int N, int FT, int fo,
    float* __restrict__ out32, _Float16* __restrict__ out16)
{
    const int G = 64 / LPR;        // sub-groups
    const int STEP = 4 * G;        // edges per wave iteration
    int node = blockIdx.x * 4 + (threadIdx.x >> 6);
    if (node >= N) return;
    int lane = threadIdx.x & 63;
    int sub = lane / LPR;
    int fl  = lane % LPR;
    const int fcol = fo + fl * 8;

    float dc = dinv[node];
    int cnt = min(deg[node], CAP);
    const int beg = node * CAP;

    float acc[8];
    if (sub == 0) {
        h8 v = *reinterpret_cast<const h8*>(&Y[(long)node * FT + fcol]);
        #pragma unroll
        for (int j = 0; j < 8; j++) acc[j] = dc * (float)v[j];
    } else {
        #pragma unroll
        for (int j = 0; j < 8; j++) acc[j] = 0.f;
    }

    int basea = cnt & ~(STEP - 1);
    for (int i = sub * 4; i < basea; i += STEP) {
        int4 r4 = *reinterpret_cast<const int4*>(&srcidx[beg + i]);
        float d0 = dinv[r4.x], d1 = dinv[r4.y], d2 = dinv[r4.z], d3 = dinv[r4.w];
        h8 v0 = *reinterpret_cast<const h8*>(&Y[(long)r4.x * FT + fcol]);
        h8 v1 = *reinterpret_cast<const h8*>(&Y[(long)r4.y * FT + fcol]);
        h8 v2 = *reinterpret_cast<const h8*>(&Y[(long)r4.z * FT + fcol]);
        h8 v3 = *reinterpret_cast<const h8*>(&Y[(long)r4.w * FT + fcol]);
        #pragma unroll
        for (int j = 0; j < 8; j++) {
            acc[j] = fmaf(d0, (float)v0[j], acc[j]);
            acc[j] = fmaf(d1, (float)v1[j], acc[j]);
            acc[j] = fmaf(d2, (float)v2[j], acc[j]);
            acc[j] = fmaf(d3, (float)v3[j], acc[j]);
        }
    }
    for (int i = basea + sub; i < cnt; i += G) {
        int r = srcidx[beg + i];
        float d = dinv[r];
        h8 v = *reinterpret_cast<const h8*>(&Y[(long)r * FT + fcol]);
        #pragma unroll
        for (int j = 0; j < 8; j++) acc[j] = fmaf(d, (float)v[j], acc[j]);
    }
    {   // capacity-overflow edges (normally ~10 entries)
        int no = *govf;
        for (int t = sub; t < no; t += G) {
            int2 pr = ovf[t];
            if (pr.y == node) {
                float d = dinv[pr.x];
                h8 v = *reinterpret_cast<const h8*>(&Y[(long)pr.x * FT + fcol]);
                #pragma unroll
                for (int j = 0; j < 8; j++) acc[j] = fmaf(d, (float)v[j], acc[j]);
            }
        }
    }

    #pragma unroll
    for (int m = LPR; m < 64; m <<= 1)
        #pragma unroll
        for (int j = 0; j < 8; j++)
            acc[j] += __shfl_xor(acc[j], m, 64);

    const float4* b4 = reinterpret_cast<const float4*>(&bias[fcol]);
    float4 blo = b4[0], bhi = b4[1];
    float r8[8];
    r8[0] = fmaf(dc, acc[0], blo.x); r8[1] = fmaf(dc, acc[1], blo.y);
    r8[2] = fmaf(dc, acc[2], blo.z); r8[3] = fmaf(dc, acc[3], blo.w);
    r8[4] = fmaf(dc, acc[4], bhi.x); r8[5] = fmaf(dc, acc[5], bhi.y);
    r8[6] = fmaf(dc, acc[6], bhi.z); r8[7] = fmaf(dc, acc[7], bhi.w);
    if (RELU) {
        #pragma unroll
        for (int j = 0; j < 8; j++) r8[j] = fmaxf(r8[j], 0.f);
    }

    long base = (long)node * FT + fcol;
    if (F16OUT) {
        if (sub == 0) {
            h8 o;
            #pragma unroll
            for (int j = 0; j < 8; j++) o[j] = (_Float16)r8[j];
            *reinterpret_cast<h8*>(&out16[base]) = o;
        }
    } else {
        if (sub == 0) {
            *reinterpret_cast<float4*>(&out32[base]) =
                make_float4(r8[0], r8[1], r8[2], r8[3]);
        } else if (sub == 1) {
            *reinterpret_cast<float4*>(&out32[base + 4]) =
                make_float4(r8[4], r8[5], r8[6], r8[7]);
        }
    }
}

extern "C" void kernel_launch(void* const* d_in, const int* in_sizes, int n_in,
                              void* d_out, int out_size, void* d_ws, size_t ws_size,
                              hipStream_t stream)
{
    const float* x   = (const float*)d_in[0];
    const int*   ei  = (const int*)d_in[1];
    const float* W1  = (const float*)d_in[2];
    const float* b1  = (const float*)d_in[3];
    const float* W2  = (const float*)d_in[4];
    const float* b2  = (const float*)d_in[5];

    const int nhid  = in_sizes[3];            // 256
    const int nfeat = in_sizes[5];            // 128
    const int N     = in_sizes[0] / nhid;     // 50000
    const int E     = in_sizes[1] / 2;        // 800000

    const int* row = ei;        // source
    const int* col = ei + E;    // target

    size_t cur = 0;
    auto alloc = [&](size_t bytes) {
        void* p = (char*)d_ws + cur;
        cur += (bytes + 255) & ~(size_t)255;
        return p;
    };
    int*       deg_i  = (int*)alloc((size_t)N * 4);
    int*       govf   = (int*)alloc(256);
    float*     dinv   = (float*)alloc((size_t)N * 4);
    int*       rank   = (int*)alloc((size_t)E * 4);
    int*       srcidx = (int*)alloc((size_t)N * CAP * 4);
    int2*      ovf    = (int2*)alloc((size_t)E * 8);
    _Float16*  wt1    = (_Float16*)alloc((size_t)nhid * nhid * 2);
    _Float16*  wt2    = (_Float16*)alloc((size_t)nhid * nfeat * 2);
    _Float16*  y16    = (_Float16*)alloc((size_t)N * nhid * 2);   // xw (unscaled)
    _Float16*  h16    = (_Float16*)alloc((size_t)N * nhid * 2);   // relu output
    _Float16*  y2     = (_Float16*)alloc((size_t)N * nfeat * 2);  // hw (unscaled)
    float*     out    = (float*)d_out;
    (void)ws_size; (void)n_in; (void)out_size;

    const int T = 256;
    const int zb  = (N + T - 1) / T;
    const int zb5 = (N + 511) / 512;
    const int gy  = (N + 127) / 128;

    // ---- zero deg/govf + weight transposes (one launch) ----
    {
        int pb = (nhid * (nhid + nfeat) + T - 1) / T;
        k_zero_prep<<<zb + pb, T, 0, stream>>>(deg_i, govf, N, W1, W2, wt1, wt2,
                                               nhid, nhid, nfeat, zb);
    }

    // ---- pure count at full wave-slot saturation ----
    k_count<<<2048, T, 0, stream>>>(col, E, deg_i, rank);

    // ---- fused (512 thr): GEMM1 wide tiles || dinv || slot fill ----
    {
        int ngb = gy;   // 391 tiles cover full 50000x256 output
        k_gemm_fill<<<ngb + zb5 + 1024, 512, 0, stream>>>(
            x, wt1, y16, N, nhid, ngb,
            row, col, rank, E, deg_i, dinv, N, srcidx, ovf, govf, zb5);
    }

    // ---- layer 1 aggregation: two SEQUENTIAL 128-wide passes ----
    {
        int nblk = (N + 3) / 4;
        k_agg<16, true, true><<<nblk, T, 0, stream>>>(
            deg_i, dinv, srcidx, ovf, govf, y16, b1, N, nhid, 0, nullptr, h16);
        k_agg<16, true, true><<<nblk, T, 0, stream>>>(
            deg_i, dinv, srcidx, ovf, govf, y16, b1, N, nhid, 128, nullptr, h16);
    }

    // ---- layer 2 ----
    {
        dim3 grid(nfeat / 128, (N + 127) / 128);
        k_gemm16<<<grid, T, 0, stream>>>(h16, wt2, y2, N, nhid, nfeat);
    }
    // ---- layer 2 aggregation: two SEQUENTIAL 64-wide passes ----
    {
        int nblk = (N + 3) / 4;
        k_agg<8, false, false><<<nblk, T, 0, stream>>>(
            deg_i, dinv, srcidx, ovf, govf, y2, b2, N, nfeat, 0, out, nullptr);
        k_agg<8, false, false><<<nblk, T, 0, stream>>>(
            deg_i, dinv, srcidx, ovf, govf, y2, b2, N, nfeat, 64, out, nullptr);
    }
}

// Round 18
// 176.898 us; speedup vs baseline: 1.2174x; 1.2174x over previous
//
#include <hip/hip_runtime.h>
#include <math.h>

// ---------------------------------------------------------------------------
// 2-layer GCN:  out = gcn(relu(gcn(x, W1, b1)), W2, b2)
// gcn(x,W,b)[c] = dinv[c] * ( dinv[c]*xw[c] + sum_{edges r->c} dinv[r]*xw[r] ) + b
//   where xw = x @ W (UNSCALED in y buffers), dinv = rsqrt(1 + indeg)
// Slot-CSR via two-pass rank build (CAP=64 — CAP=32 regressed agg, R17).
// GEMM1 tile = 128x256 (FULL output width, 512 thr / 8 waves): x read ONCE.
// zero -> count(1024)+W-prep -> GEMM1||dinv||fill -> agg1 h0 -> agg1 h1 ->
// GEMM2 -> agg2.   [R16 best-measured config: 177.1 us]
// ---------------------------------------------------------------------------

typedef _Float16 h8 __attribute__((ext_vector_type(8)));
typedef float    f32x4 __attribute__((ext_vector_type(4)));

#define CAP 64   // slots per node; overflow list handles adversarial degrees

__global__ void k_zero(int* __restrict__ deg, int* __restrict__ govf, int N) {
    int i = blockIdx.x * blockDim.x + threadIdx.x;
    if (i < N) deg[i] = 0;
    if (i == 0) *govf = 0;
}

// count (1024 blocks) + weight prep
__global__ __launch_bounds__(256) void k_count_prep(
    const int* __restrict__ col, int E, int* __restrict__ deg, int* __restrict__ rank,
    int ncb,
    const float* __restrict__ W1, const float* __restrict__ W2,
    _Float16* __restrict__ wt1, _Float16* __restrict__ wt2,
    int K, int n1, int n2)
{
    if ((int)blockIdx.x < ncb) {
        int i = blockIdx.x * blockDim.x + threadIdx.x;
        int s = ncb * blockDim.x;
        for (int e = i; e < E; e += s) rank[e] = atomicAdd(&deg[col[e]], 1);
        return;
    }
    int i = (blockIdx.x - ncb) * blockDim.x + threadIdx.x;
    int c1 = K * n1;
    if (i < c1) {
        int k = i / n1, n = i % n1;
        wt1[(long)n * K + k] = (_Float16)W1[i];
    } else if (i < c1 + K * n2) {
        int j = i - c1;
        int k = j / n2, n = j % n2;
        wt2[(long)n * K + k] = (_Float16)W2[j];
    }
}

// ---- GEMM1 body: 128x256 tile (full NC), 512 threads = 8 waves (2x4),
// each wave 64x64 via 4x4 mfma_f32_16x16x32_f16. Reads fp32 X once. ----
__device__ __forceinline__ void gemm1_body(
    const float* __restrict__ X32, const _Float16* __restrict__ Wt,
    _Float16* __restrict__ Y, int M, int K, int by)
{
    __shared__ _Float16 As[128][40];   // 10.25 KB
    __shared__ _Float16 Bs[256][40];   // 20.5 KB

    const int bm = by * 128;
    const int tid = threadIdx.x;        // 0..511
    const int w = tid >> 6, l = tid & 63;
    const int wm = (w >> 2) * 64, wn = (w & 3) * 64;
    const int lr = l & 15, lg = l >> 4;

    const int arow = tid >> 2, acol = (tid & 3) * 8;   // A: 128 x 32
    const int brow = tid >> 1, bcol = (tid & 1) * 16;  // B: 256 x 32

    f32x4 acc[4][4];
    #pragma unroll
    for (int i = 0; i < 4; i++)
        #pragma unroll
        for (int j = 0; j < 4; j++)
            acc[i][j] = (f32x4){0.f, 0.f, 0.f, 0.f};

    float4 pf0, pf1;
    h8 pb0, pb1;

    auto loadA = [&](int k0) {
        int gm = bm + arow; if (gm >= M) gm = M - 1;
        pf0 = *reinterpret_cast<const float4*>(&X32[(long)gm * K + k0 + acol]);
        pf1 = *reinterpret_cast<const float4*>(&X32[(long)gm * K + k0 + acol + 4]);
    };
    auto loadB = [&](int k0) {
        pb0 = *reinterpret_cast<const h8*>(&Wt[(long)brow * K + k0 + bcol]);
        pb1 = *reinterpret_cast<const h8*>(&Wt[(long)brow * K + k0 + bcol + 8]);
    };

    loadA(0); loadB(0);
    for (int k0 = 0; k0 < K; k0 += 32) {
        h8 hv;
        hv[0] = (_Float16)pf0.x; hv[1] = (_Float16)pf0.y;
        hv[2] = (_Float16)pf0.z; hv[3] = (_Float16)pf0.w;
        hv[4] = (_Float16)pf1.x; hv[5] = (_Float16)pf1.y;
        hv[6] = (_Float16)pf1.z; hv[7] = (_Float16)pf1.w;
        *reinterpret_cast<h8*>(&As[arow][acol]) = hv;
        *reinterpret_cast<h8*>(&Bs[brow][bcol]) = pb0;
        *reinterpret_cast<h8*>(&Bs[brow][bcol + 8]) = pb1;
        __syncthreads();

        if (k0 + 32 < K) { loadA(k0 + 32); loadB(k0 + 32); }

        h8 a[4], b[4];
        #pragma unroll
        for (int i = 0; i < 4; i++)
            a[i] = *reinterpret_cast<const h8*>(&As[wm + i * 16 + lr][lg * 8]);
        #pragma unroll
        for (int j = 0; j < 4; j++)
            b[j] = *reinterpret_cast<const h8*>(&Bs[wn + j * 16 + lr][lg * 8]);
        #pragma unroll
        for (int i = 0; i < 4; i++)
            #pragma unroll
            for (int j = 0; j < 4; j++)
                acc[i][j] = __builtin_amdgcn_mfma_f32_16x16x32_f16(
                    a[i], b[j], acc[i][j], 0, 0, 0);
        __syncthreads();
    }

    // C layout: row = (l>>4)*4 + reg, col = l&15 ; NC = 256, unscaled
    #pragma unroll
    for (int i = 0; i < 4; i++) {
        #pragma unroll
        for (int r = 0; r < 4; r++) {
            int gm = bm + wm + i * 16 + lg * 4 + r;
            if (gm < M) {
                #pragma unroll
                for (int j = 0; j < 4; j++)
                    Y[(long)gm * 256 + wn + j * 16 + lr] =
                        (_Float16)acc[i][j][r];
            }
        }
    }
}

// Fused (512 threads): blocks [0,ngb) = GEMM1 wide tiles; [ngb,ngb+zb5) =
// dinv; rest = atomic-free slot fill via rank.
__global__ __launch_bounds__(512) void k_gemm_fill(
    const float* __restrict__ X32, const _Float16* __restrict__ Wt,
    _Float16* __restrict__ Y, int M, int K, int ngb,
    const int* __restrict__ row, const int* __restrict__ col,
    const int* __restrict__ rank, int E,
    const int* __restrict__ deg, float* __restrict__ dinv, int N,
    int* __restrict__ srcidx, int2* __restrict__ ovf, int* __restrict__ govf,
    int zb5)
{
    if ((int)blockIdx.x < ngb) {
        gemm1_body(X32, Wt, Y, M, K, blockIdx.x);
        return;
    }
    if ((int)blockIdx.x < ngb + zb5) {
        int i = (blockIdx.x - ngb) * blockDim.x + threadIdx.x;
        if (i < N) dinv[i] = rsqrtf(1.f + (float)deg[i]);
        return;
    }
    int g = (blockIdx.x - ngb - zb5) * blockDim.x + threadIdx.x;
    int nthreads = (gridDim.x - ngb - zb5) * blockDim.x;
    if ((E & 3) == 0) {
        int G4 = E >> 2;
        for (int q = g; q < G4; q += nthreads) {
            int e = q << 2;
            int4 c4 = *reinterpret_cast<const int4*>(&col[e]);
            int4 r4 = *reinterpret_cast<const int4*>(&row[e]);
            int4 k4 = *reinterpret_cast<const int4*>(&rank[e]);
            if (k4.x < CAP) srcidx[c4.x * CAP + k4.x] = r4.x;
            else { int o = atomicAdd(govf, 1); ovf[o] = make_int2(r4.x, c4.x); }
            if (k4.y < CAP) srcidx[c4.y * CAP + k4.y] = r4.y;
            else { int o = atomicAdd(govf, 1); ovf[o] = make_int2(r4.y, c4.y); }
            if (k4.z < CAP) srcidx[c4.z * CAP + k4.z] = r4.z;
            else { int o = atomicAdd(govf, 1); ovf[o] = make_int2(r4.z, c4.z); }
            if (k4.w < CAP) srcidx[c4.w * CAP + k4.w] = r4.w;
            else { int o = atomicAdd(govf, 1); ovf[o] = make_int2(r4.w, c4.w); }
        }
    } else {
        for (int e = g; e < E; e += nthreads) {
            int c = col[e], r = row[e], k = rank[e];
            if (k < CAP) srcidx[c * CAP + k] = r;
            else { int o = atomicAdd(govf, 1); ovf[o] = make_int2(r, c); }
        }
    }
}

// ---- GEMM2 body: 128x128 tile, 256 threads, fp16 input ----
__global__ __launch_bounds__(256) void k_gemm16(
    const _Float16* __restrict__ X16, const _Float16* __restrict__ Wt,
    _Float16* __restrict__ Y, int M, int K, int NC)
{
    __shared__ _Float16 As[128][40];
    __shared__ _Float16 Bs[128][40];

    const int bn = blockIdx.x * 128;
    const int bm = blockIdx.y * 128;
    const int tid = threadIdx.x;
    const int w = tid >> 6, l = tid & 63;
    const int wm = (w >> 1) * 64, wn = (w & 1) * 64;
    const int lr = l & 15, lg = l >> 4;
    const int xrow = tid >> 1, xcol = (tid & 1) * 16;

    f32x4 acc[4][4];
    #pragma unroll
    for (int i = 0; i < 4; i++)
        #pragma unroll
        for (int j = 0; j < 4; j++)
            acc[i][j] = (f32x4){0.f, 0.f, 0.f, 0.f};

    h8 pa0, pa1, pb0, pb1;
    auto loadA = [&](int k0) {
        int gm = bm + xrow; if (gm >= M) gm = M - 1;
        pa0 = *reinterpret_cast<const h8*>(&X16[(long)gm * K + k0 + xcol]);
        pa1 = *reinterpret_cast<const h8*>(&X16[(long)gm * K + k0 + xcol + 8]);
    };
    auto loadB = [&](int k0) {
        pb0 = *reinterpret_cast<const h8*>(&Wt[(long)(bn + xrow) * K + k0 + xcol]);
        pb1 = *reinterpret_cast<const h8*>(&Wt[(long)(bn + xrow) * K + k0 + xcol + 8]);
    };

    loadA(0); loadB(0);
    for (int k0 = 0; k0 < K; k0 += 32) {
        *reinterpret_cast<h8*>(&As[xrow][xcol]) = pa0;
        *reinterpret_cast<h8*>(&As[xrow][xcol + 8]) = pa1;
        *reinterpret_cast<h8*>(&Bs[xrow][xcol]) = pb0;
        *reinterpret_cast<h8*>(&Bs[xrow][xcol + 8]) = pb1;
        __syncthreads();

        if (k0 + 32 < K) { loadA(k0 + 32); loadB(k0 + 32); }

        h8 a[4], b[4];
        #pragma unroll
        for (int i = 0; i < 4; i++)
            a[i] = *reinterpret_cast<const h8*>(&As[wm + i * 16 + lr][lg * 8]);
        #pragma unroll
        for (int j = 0; j < 4; j++)
            b[j] = *reinterpret_cast<const h8*>(&Bs[wn + j * 16 + lr][lg * 8]);
        #pragma unroll
        for (int i = 0; i < 4; i++)
            #pragma unroll
            for (int j = 0; j < 4; j++)
                acc[i][j] = __builtin_amdgcn_mfma_f32_16x16x32_f16(
                    a[i], b[j], acc[i][j], 0, 0, 0);
        __syncthreads();
    }

    #pragma unroll
    for (int i = 0; i < 4; i++) {
        #pragma unroll
        for (int r = 0; r < 4; r++) {
            int gm = bm + wm + i * 16 + lg * 4 + r;
            if (gm < M) {
                #pragma unroll
                for (int j = 0; j < 4; j++)
                    Y[(long)gm * NC + bn + wn + j * 16 + lr] =
                        (_Float16)acc[i][j][r];
            }
        }
    }
}

// out[node][fo:fo+128] = act( dc*( dc*Y[node] + sum_e dinv[r]*Y[r] ) + bias )
// One wave per node, slot-CSR; 16 lanes/row slice, 4 sub-groups; int4 slot
// loads (16 edges in flight); fp16-source fma.
template<bool F16OUT, bool RELU>
__global__ __launch_bounds__(256) void k_agg(
    const int* __restrict__ deg, const float* __restrict__ dinv,
    const int* __restrict__ srcidx,
    const int2* __restrict__ ovf, const int* __restrict__ govf,
    const _Float16* __restrict__ Y, const float* __restrict__ bias,
    int N, int FT, int fo,
    float* __restrict__ out32, _Float16* __restrict__ out16)
{
    int node = blockIdx.x * 4 + (threadIdx.x >> 6);
    if (node >= N) return;
    int lane = threadIdx.x & 63;
    int sub = lane >> 4;
    int fl  = lane & 15;
    const int fcol = fo + fl * 8;

    float dc = dinv[node];
    int cnt = min(deg[node], CAP);
    const int beg = node * CAP;

    float acc[8];
    if (sub == 0) {
        h8 v = *reinterpret_cast<const h8*>(&Y[(long)node * FT + fcol]);
        #pragma unroll
        for (int j = 0; j < 8; j++) acc[j] = dc * (float)v[j];
    } else {
        #pragma unroll
        for (int j = 0; j < 8; j++) acc[j] = 0.f;
    }

    int base16 = cnt & ~15;
    for (int i = sub * 4; i < base16; i += 16) {
        int4 r4 = *reinterpret_cast<const int4*>(&srcidx[beg + i]);
        float d0 = dinv[r4.x], d1 = dinv[r4.y], d2 = dinv[r4.z], d3 = dinv[r4.w];
        h8 v0 = *reinterpret_cast<const h8*>(&Y[(long)r4.x * FT + fcol]);
        h8 v1 = *reinterpret_cast<const h8*>(&Y[(long)r4.y * FT + fcol]);
        h8 v2 = *reinterpret_cast<const h8*>(&Y[(long)r4.z * FT + fcol]);
        h8 v3 = *reinterpret_cast<const h8*>(&Y[(long)r4.w * FT + fcol]);
        #pragma unroll
        for (int j = 0; j < 8; j++) {
            acc[j] = fmaf(d0, (float)v0[j], acc[j]);
            acc[j] = fmaf(d1, (float)v1[j], acc[j]);
            acc[j] = fmaf(d2, (float)v2[j], acc[j]);
            acc[j] = fmaf(d3, (float)v3[j], acc[j]);
        }
    }
    for (int i = base16 + sub; i < cnt; i += 4) {
        int r = srcidx[beg + i];
        float d = dinv[r];
        h8 v = *reinterpret_cast<const h8*>(&Y[(long)r * FT + fcol]);
        #pragma unroll
        for (int j = 0; j < 8; j++) acc[j] = fmaf(d, (float)v[j], acc[j]);
    }
    {
        int no = *govf;
        for (int t = sub; t < no; t += 4) {
            int2 pr = ovf[t];
            if (pr.y == node) {
                float d = dinv[pr.x];
                h8 v = *reinterpret_cast<const h8*>(&Y[(long)pr.x * FT + fcol]);
                #pragma unroll
                for (int j = 0; j < 8; j++) acc[j] = fmaf(d, (float)v[j], acc[j]);
            }
        }
    }

    #pragma unroll
    for (int m = 16; m < 64; m <<= 1)
        #pragma unroll
        for (int j = 0; j < 8; j++)
            acc[j] += __shfl_xor(acc[j], m, 64);

    const float4* b4 = reinterpret_cast<const float4*>(&bias[fcol]);
    float4 blo = b4[0], bhi = b4[1];
    float r8[8];
    r8[0] = fmaf(dc, acc[0], blo.x); r8[1] = fmaf(dc, acc[1], blo.y);
    r8[2] = fmaf(dc, acc[2], blo.z); r8[3] = fmaf(dc, acc[3], blo.w);
    r8[4] = fmaf(dc, acc[4], bhi.x); r8[5] = fmaf(dc, acc[5], bhi.y);
    r8[6] = fmaf(dc, acc[6], bhi.z); r8[7] = fmaf(dc, acc[7], bhi.w);
    if (RELU) {
        #pragma unroll
        for (int j = 0; j < 8; j++) r8[j] = fmaxf(r8[j], 0.f);
    }

    long base = (long)node * FT + fcol;
    if (F16OUT) {
        if (sub == 0) {
            h8 o;
            #pragma unroll
            for (int j = 0; j < 8; j++) o[j] = (_Float16)r8[j];
            *reinterpret_cast<h8*>(&out16[base]) = o;
        }
    } else {
        if (sub == 0) {
            *reinterpret_cast<float4*>(&out32[base]) =
                make_float4(r8[0], r8[1], r8[2], r8[3]);
        } else if (sub == 1) {
            *reinterpret_cast<float4*>(&out32[base + 4]) =
                make_float4(r8[4], r8[5], r8[6], r8[7]);
        }
    }
}

extern "C" void kernel_launch(void* const* d_in, const int* in_sizes, int n_in,
                              void* d_out, int out_size, void* d_ws, size_t ws_size,
                              hipStream_t stream)
{
    const float* x   = (const float*)d_in[0];
    const int*   ei  = (const int*)d_in[1];
    const float* W1  = (const float*)d_in[2];
    const float* b1  = (const float*)d_in[3];
    const float* W2  = (const float*)d_in[4];
    const float* b2  = (const float*)d_in[5];

    const int nhid  = in_sizes[3];            // 256
    const int nfeat = in_sizes[5];            // 128
    const int N     = in_sizes[0] / nhid;     // 50000
    const int E     = in_sizes[1] / 2;        // 800000

    const int* row = ei;        // source
    const int* col = ei + E;    // target

    size_t cur = 0;
    auto alloc = [&](size_t bytes) {
        void* p = (char*)d_ws + cur;
        cur += (bytes + 255) & ~(size_t)255;
        return p;
    };
    int*       deg_i  = (int*)alloc((size_t)N * 4);
    int*       govf   = (int*)alloc(256);
    float*     dinv   = (float*)alloc((size_t)N * 4);
    int*       rank   = (int*)alloc((size_t)E * 4);
    int*       srcidx = (int*)alloc((size_t)N * CAP * 4);
    int2*      ovf    = (int2*)alloc((size_t)E * 8);
    _Float16*  wt1    = (_Float16*)alloc((size_t)nhid * nhid * 2);
    _Float16*  wt2    = (_Float16*)alloc((size_t)nhid * nfeat * 2);
    _Float16*  y16    = (_Float16*)alloc((size_t)N * nhid * 2);   // xw (unscaled)
    _Float16*  h16    = (_Float16*)alloc((size_t)N * nhid * 2);   // relu output
    _Float16*  y2     = (_Float16*)alloc((size_t)N * nfeat * 2);  // hw (unscaled)
    float*     out    = (float*)d_out;
    (void)ws_size; (void)n_in; (void)out_size;

    const int T = 256;
    const int zb  = (N + T - 1) / T;
    const int zb5 = (N + 511) / 512;
    const int gy  = (N + 127) / 128;

    // ---- zero deg/govf ----
    k_zero<<<zb, T, 0, stream>>>(deg_i, govf, N);

    // ---- count (1024 blocks) + weight prep ----
    {
        const int ncb = 1024;
        int pb = (nhid * (nhid + nfeat) + T - 1) / T;
        k_count_prep<<<ncb + pb, T, 0, stream>>>(
            col, E, deg_i, rank, ncb, W1, W2, wt1, wt2, nhid, nhid, nfeat);
    }

    // ---- fused (512 thr): GEMM1 wide tiles || dinv || slot fill ----
    {
        int ngb = gy;   // 391 tiles cover full 50000x256 output
        k_gemm_fill<<<ngb + zb5 + 1024, 512, 0, stream>>>(
            x, wt1, y16, N, nhid, ngb,
            row, col, rank, E, deg_i, dinv, N, srcidx, ovf, govf, zb5);
    }

    // ---- layer 1 aggregation: two SEQUENTIAL feature-half passes ----
    {
        int nblk = (N + 3) / 4;
        k_agg<true, true><<<nblk, T, 0, stream>>>(
            deg_i, dinv, srcidx, ovf, govf, y16, b1, N, nhid, 0, nullptr, h16);
        k_agg<true, true><<<nblk, T, 0, stream>>>(
            deg_i, dinv, srcidx, ovf, govf, y16, b1, N, nhid, 128, nullptr, h16);
    }

    // ---- layer 2 ----
    {
        dim3 grid(nfeat / 128, (N + 127) / 128);
        k_gemm16<<<grid, T, 0, stream>>>(h16, wt2, y2, N, nhid, nfeat);
    }
    {
        int nblk = (N + 3) / 4;
        k_agg<false, false><<<nblk, T, 0, stream>>>(
            deg_i, dinv, srcidx, ovf, govf, y2, b2, N, nfeat, 0, out, nullptr);
    }
}